// Round 4
// baseline (227.673 us; speedup 1.0000x reference)
//
#include <hip/hip_runtime.h>
#include <math.h>

// Problem constants (fixed by the reference)
#define NN 131072
#define KK 1024
#define DD 64
#define GAMMA 0.99f
#define ALPHA 1e-9f
#define BETA 0.25f

typedef float f32x4 __attribute__((ext_vector_type(4)));
typedef short bf16x8 __attribute__((ext_vector_type(8)));

typedef const __attribute__((address_space(1))) void gv_t;
typedef __attribute__((address_space(3))) void lv_t;

__device__ __constant__ float OMG = (float)(1.0 - 0.99);

// split fp32 -> hi (truncated bf16) + lo (RNE bf16 of residual)
__device__ __forceinline__ void split_bf16(float v, unsigned short& h, unsigned short& l) {
    unsigned int b = __float_as_uint(v);
    unsigned int hb = b & 0xFFFF0000u;
    h = (unsigned short)(hb >> 16);
    float r = v - __uint_as_float(hb);
    unsigned int lb = __float_as_uint(r);
    lb += 0x7FFFu + ((lb >> 16) & 1u);
    l = (unsigned short)(lb >> 16);
}

// ---------------------------------------------------------------------------
// Prep: build E B-fragments in MFMA layout (hi/lo split) + esqh = -|e|^2/2.
// ---------------------------------------------------------------------------
__global__ __launch_bounds__(64)
void vq_prep(const float* __restrict__ E, float4* __restrict__ Efrag,
             float* __restrict__ esqh) {
    int nt = blockIdx.x;
    int l = threadIdx.x;
    int n = nt * 16 + (l & 15);
    int kb = (l >> 4) * 8;
    float ss = 0.f;
    #pragma unroll
    for (int ks = 0; ks < 2; ++ks) {
        const float4* xp = (const float4*)(E + (size_t)n * DD + ks * 32 + kb);
        float4 a = xp[0], b = xp[1];
        float v[8] = {a.x, a.y, a.z, a.w, b.x, b.y, b.z, b.w};
        union { float4 f; unsigned short u[8]; } H, L;
        #pragma unroll
        for (int j = 0; j < 8; ++j) {
            unsigned short hh, ll;
            split_bf16(v[j], hh, ll);
            H.u[j] = hh; L.u[j] = ll;
            ss = fmaf(v[j], v[j], ss);
        }
        int fid = nt * 4 + ks * 2;
        Efrag[(size_t)(fid + 0) * 64 + l] = H.f;
        Efrag[(size_t)(fid + 1) * 64 + l] = L.f;
    }
    ss += __shfl_xor(ss, 16, 64);
    ss += __shfl_xor(ss, 32, 64);
    if (l < 16) esqh[nt * 16 + l] = -0.5f * ss;   // MFMA C-init: score = d - esq/2
}

// ---------------------------------------------------------------------------
// Main: split-bf16 MFMA distance GEMM + argmax(score) + epilogue.
//
// R4: move the segment-sum into this kernel. R0-R3 showed vq_main's pipes
// each ~25% busy (serialized, not a BW wall); meanwhile ~60-70us hid in
// vq_sum_ema's random-rowlist re-read of all of X (33.5MB gathered 256B
// rows, latency-bound). Phase C already touches every X row's cacheline
// footprint; make the X read unconditional and atomicAdd each row into
// sums[code] directly (131K wave-atomics, vmem pipe is 75% idle). rowlist/
// cap/fbflag machinery deleted; vq_sum_ema shrinks to a ~5us finalize.
// ---------------------------------------------------------------------------
#define BM 64

__global__ __launch_bounds__(256, 4)
void vq_main(const float* __restrict__ X, const float* __restrict__ E,
             const float4* __restrict__ Efrag, const float* __restrict__ esqh,
             float* __restrict__ argf, float* __restrict__ mind,
             float* __restrict__ Z, int* __restrict__ cursor,
             float* __restrict__ sums, float* __restrict__ loss_part) {
    __shared__ float4 stg[2][8][64];   // [buf][cg*4+fid][lane], 2 x 8KB
    __shared__ float redv[128];   // 64 rows x 2 col-groups
    __shared__ int redi[128];
    __shared__ int bidx[64];
    __shared__ float bsc[64];
    __shared__ float xsqs[64];

    int tid = threadIdx.x;
    int lane = tid & 63, w = tid >> 6;
    int rg = w & 1, cg = w >> 1;
    int lc = lane & 15, lq = lane >> 4;

    size_t bb = (size_t)blockIdx.x * BM;
    size_t R0 = bb + rg * 32;

    // de-phase: blocks on the same XCD get consecutive start offsets in the
    // circular col-tile order
    int st = (blockIdx.x >> 3) & 31;

    // wave w stages fragments {w*2, w*2+1} of the 8-fragment (8KB) tile-pair
    auto stage_tile = [&](float4 (*sb)[64], int nt) {
        int cgs = w >> 1, fp = (w & 1) * 2;
        const float4* gp = Efrag + ((size_t)(cgs * 32 + nt)) * 256 + fp * 64 + lane;
        __builtin_amdgcn_global_load_lds((gv_t*)gp,
                                         (lv_t*)&sb[cgs * 4 + fp][0], 16, 0, 0);
        __builtin_amdgcn_global_load_lds((gv_t*)(gp + 64),
                                         (lv_t*)&sb[cgs * 4 + fp + 1][0], 16, 0, 0);
    };

    // issue the first stage ASAP; the A-fragment build below covers its latency
    stage_tile(stg[0], st);

    // A fragments: 2 m-tiles x 2 k-steps, hi+lo (32 VGPRs) + exact xsq
    bf16x8 ah[2][2], al[2][2];
    #pragma unroll
    for (int mt = 0; mt < 2; ++mt) {
        float xq = 0.f;
        #pragma unroll
        for (int ks = 0; ks < 2; ++ks) {
            const float4* xp =
                (const float4*)(X + (R0 + mt * 16 + lc) * DD + ks * 32 + lq * 8);
            float4 x0 = xp[0], x1 = xp[1];
            float v[8] = {x0.x, x0.y, x0.z, x0.w, x1.x, x1.y, x1.z, x1.w};
            union { bf16x8 s; unsigned short u[8]; } H, L;
            #pragma unroll
            for (int j = 0; j < 8; ++j) {
                unsigned short hh, ll;
                split_bf16(v[j], hh, ll);
                H.u[j] = hh; L.u[j] = ll;
                xq = fmaf(v[j], v[j], xq);
            }
            ah[mt][ks] = H.s;
            al[mt][ks] = L.s;
        }
        xq += __shfl_xor(xq, 16, 64);
        xq += __shfl_xor(xq, 32, 64);
        if (lane < 16) xsqs[rg * 32 + mt * 16 + lane] = xq;
    }

    float bestv[2][4];
    int besti[2][4];
    #pragma unroll
    for (int mt = 0; mt < 2; ++mt)
        #pragma unroll
        for (int r = 0; r < 4; ++r) { bestv[mt][r] = -3.402823466e38f; besti[mt][r] = 0; }

    const float* ep = esqh + cg * 512 + lc;

    // consume one staged 16-col tile: 4x ds_read_b128 + 12 MFMA + best-update
    auto consume = [&](float4 (*sb)[64], int ntp) {
        float ec = ep[ntp * 16];
        union { float4 f; bf16x8 s; } u0, u1, u2, u3;
        u0.f = sb[cg * 4 + 0][lane];
        u1.f = sb[cg * 4 + 1][lane];
        u2.f = sb[cg * 4 + 2][lane];
        u3.f = sb[cg * 4 + 3][lane];
        f32x4 acc[2];
        #pragma unroll
        for (int mt = 0; mt < 2; ++mt) acc[mt] = (f32x4){ec, ec, ec, ec};
        #pragma unroll
        for (int mt = 0; mt < 2; ++mt)
            acc[mt] = __builtin_amdgcn_mfma_f32_16x16x32_bf16(ah[mt][0], u0.s, acc[mt], 0, 0, 0);
        #pragma unroll
        for (int mt = 0; mt < 2; ++mt)
            acc[mt] = __builtin_amdgcn_mfma_f32_16x16x32_bf16(ah[mt][1], u2.s, acc[mt], 0, 0, 0);
        #pragma unroll
        for (int mt = 0; mt < 2; ++mt)
            acc[mt] = __builtin_amdgcn_mfma_f32_16x16x32_bf16(ah[mt][0], u1.s, acc[mt], 0, 0, 0);
        #pragma unroll
        for (int mt = 0; mt < 2; ++mt)
            acc[mt] = __builtin_amdgcn_mfma_f32_16x16x32_bf16(ah[mt][1], u3.s, acc[mt], 0, 0, 0);
        #pragma unroll
        for (int mt = 0; mt < 2; ++mt)
            acc[mt] = __builtin_amdgcn_mfma_f32_16x16x32_bf16(al[mt][0], u0.s, acc[mt], 0, 0, 0);
        #pragma unroll
        for (int mt = 0; mt < 2; ++mt)
            acc[mt] = __builtin_amdgcn_mfma_f32_16x16x32_bf16(al[mt][1], u2.s, acc[mt], 0, 0, 0);
        int n = cg * 512 + ntp * 16 + lc;
        #pragma unroll
        for (int mt = 0; mt < 2; ++mt)
            #pragma unroll
            for (int r = 0; r < 4; ++r) {
                float sc = acc[mt][r];
                if (sc > bestv[mt][r]) { bestv[mt][r] = sc; besti[mt][r] = n; }
            }
    };

    // double-buffered sweep: barrier (drains stage of cur), issue stage of
    // next into the other buffer, then compute cur
    for (int i = 0; i < 32; i += 2) {
        __syncthreads();                       // stg[0] (tile i) ready
        stage_tile(stg[1], (i + 1 + st) & 31); // async: next tile
        consume(stg[0], (i + st) & 31);
        __syncthreads();                       // stg[1] (tile i+1) ready
        if (i + 2 < 32) stage_tile(stg[0], (i + 2 + st) & 31);
        consume(stg[1], (i + 1 + st) & 31);
    }

    // reduce across the 16 lanes holding one row (max score, low-index ties)
    #pragma unroll
    for (int off = 1; off <= 8; off <<= 1) {
        #pragma unroll
        for (int mt = 0; mt < 2; ++mt) {
            #pragma unroll
            for (int r = 0; r < 4; ++r) {
                float ov = __shfl_xor(bestv[mt][r], off, 64);
                int oi = __shfl_xor(besti[mt][r], off, 64);
                if (ov > bestv[mt][r] || (ov == bestv[mt][r] && oi < besti[mt][r])) {
                    bestv[mt][r] = ov; besti[mt][r] = oi;
                }
            }
        }
    }
    if (lc == 0) {
        #pragma unroll
        for (int mt = 0; mt < 2; ++mt)
            #pragma unroll
            for (int r = 0; r < 4; ++r) {
                int row = rg * 32 + mt * 16 + lq * 4 + r;
                redv[row * 2 + cg] = bestv[mt][r];
                redi[row * 2 + cg] = besti[mt][r];
            }
    }
    __syncthreads();
    if (tid < 64) {
        float v0 = redv[tid * 2], v1 = redv[tid * 2 + 1];
        int i0 = redi[tid * 2], i1 = redi[tid * 2 + 1];
        int pick = (v1 > v0 || (v1 == v0 && i1 < i0));
        bidx[tid] = pick ? i1 : i0;
        bsc[tid] = pick ? v1 : v0;
    }
    __syncthreads();

    // Phase B: one row per lane of wave 0 -> 64 concurrent cursor atomics
    if (tid < 64) {
        int row = tid;
        int bi = bidx[row];
        size_t grow = bb + row;
        float md = fmaf(-2.f, bsc[row], xsqs[row]);  // dist = xsq - 2*best
        mind[grow] = md;
        argf[grow] = (float)bi;
        atomicAdd(&cursor[bi], 1);
        #pragma unroll
        for (int m = 32; m; m >>= 1) md += __shfl_xor(md, m, 64);
        if (tid == 0) atomicAdd(&loss_part[blockIdx.x & 1023], md);
    }
    __syncthreads();

    // Phase C: Z = E[argmin] gather + direct segment-sum accumulation.
    // X row is L3-hot (read in prologue); atomics go to 1024x4 L2 lines.
    #pragma unroll 4
    for (int it = 0; it < 16; ++it) {
        int row = w * 16 + it;
        int bi = bidx[row];
        size_t grow = bb + row;
        float e = E[(size_t)bi * DD + lane];
        float x = X[grow * DD + lane];
        Z[grow * DD + lane] = e;
        atomicAdd(&sums[(size_t)bi * DD + lane], x);
    }
}

// ---------------------------------------------------------------------------
// Finalize: cs + loss + ma/E_new from the atomically-built sums. 256 blocks
// x 256 threads; wave j of block b owns code k = b*4+j (64 lanes = 64 dims).
// ---------------------------------------------------------------------------
__global__ __launch_bounds__(256)
void vq_ema(const int* __restrict__ cursor, const float* __restrict__ sums,
            const float* __restrict__ cluster_sizes,
            const float* __restrict__ loss_part, const float* __restrict__ mavg,
            float* __restrict__ o_ma, float* __restrict__ o_enew,
            float* __restrict__ o_cs, float* __restrict__ o_loss) {
    __shared__ float redt[4];
    int tid = threadIdx.x, lane = tid & 63, w = tid >> 6;
    int k = blockIdx.x * 4 + w;

    // global total = sum_j gamma*cluster_sizes[j] + (1-gamma)*counts[j]
    float t = 0.f;
    #pragma unroll
    for (int j = 0; j < 4; ++j) {
        int c = tid + j * 256;
        t += GAMMA * cluster_sizes[c] + OMG * (float)cursor[c];
    }
    #pragma unroll
    for (int m = 32; m; m >>= 1) t += __shfl_xor(t, m, 64);
    if (lane == 0) redt[w] = t;
    __syncthreads();
    float total = redt[0] + redt[1] + redt[2] + redt[3];

    float csr = GAMMA * cluster_sizes[k] + OMG * (float)cursor[k];
    float cs = (csr + ALPHA) / (1.0f + (ALPHA * (float)KK) / total);
    if (lane == 0) o_cs[k] = cs;

    float s = sums[(size_t)k * DD + lane];
    float ma = GAMMA * mavg[(size_t)k * DD + lane] + OMG * s;
    o_ma[(size_t)k * DD + lane] = ma;
    o_enew[(size_t)k * DD + lane] = ma / cs;

    if (blockIdx.x == 0) {   // loss finalize: reduce 1024 loss_part entries
        float l = 0.f;
        #pragma unroll
        for (int j = 0; j < 4; ++j) l += loss_part[tid + j * 256];
        #pragma unroll
        for (int m = 32; m; m >>= 1) l += __shfl_xor(l, m, 64);
        __syncthreads();   // redt free again (total already consumed)
        if (lane == 0) redt[w] = l;
        __syncthreads();
        if (tid == 0)
            o_loss[0] = BETA * ((redt[0] + redt[1] + redt[2] + redt[3]) / (float)NN);
    }
}

// ---------------------------------------------------------------------------
extern "C" void kernel_launch(void* const* d_in, const int* in_sizes, int n_in,
                              void* d_out, int out_size, void* d_ws, size_t ws_size,
                              hipStream_t stream) {
    const float* X = (const float*)d_in[0];
    const float* E = (const float*)d_in[1];
    const float* cluster_sizes = (const float*)d_in[2];
    const float* moving_avg = (const float*)d_in[3];

    // Output layout: Z[N*D], loss[1], argmins[N], min_dist[N],
    //                E_new[K*D], cs[K], ma[K*D]
    float* out = (float*)d_out;
    float* o_Z = out;
    float* o_loss = o_Z + (size_t)NN * DD;
    float* o_arg = o_loss + 1;
    float* o_mind = o_arg + NN;
    float* o_enew = o_mind + NN;
    float* o_cs = o_enew + (size_t)KK * DD;
    float* o_ma = o_cs + KK;

    // Workspace (4B units):
    // [cursor 1024 i32][loss_part 1024 f][sums 65536 f][esqh 1024 f]
    // [Efrag 65536 f]
    int* cursor = (int*)d_ws;
    float* loss_part = (float*)d_ws + 1024;
    float* sums = loss_part + 1024;
    float* esqh = sums + (size_t)KK * DD;
    float4* Efrag = (float4*)(esqh + KK);

    // zero cursor + loss_part + sums (contiguous prefix)
    hipMemsetAsync(d_ws, 0, (size_t)(1024 + 1024 + KK * DD) * 4, stream);

    vq_prep<<<KK / 16, 64, 0, stream>>>(E, Efrag, esqh);
    vq_main<<<NN / BM, 256, 0, stream>>>(X, E, Efrag, esqh, o_arg, o_mind, o_Z,
                                         cursor, sums, loss_part);
    vq_ema<<<KK / 4, 256, 0, stream>>>(cursor, sums, cluster_sizes, loss_part,
                                       moving_avg, o_ma, o_enew, o_cs, o_loss);
}

// Round 5
// 199.940 us; speedup vs baseline: 1.1387x; 1.1387x over previous
//
#include <hip/hip_runtime.h>
#include <math.h>

// Problem constants (fixed by the reference)
#define NN 131072
#define KK 1024
#define DD 64
#define GAMMA 0.99f
#define ALPHA 1e-9f
#define BETA 0.25f

typedef float f32x4 __attribute__((ext_vector_type(4)));
typedef short bf16x8 __attribute__((ext_vector_type(8)));

typedef const __attribute__((address_space(1))) void gv_t;
typedef __attribute__((address_space(3))) void lv_t;

__device__ __constant__ float OMG = (float)(1.0 - 0.99);

// split fp32 -> hi (truncated bf16) + lo (RNE bf16 of residual)
__device__ __forceinline__ void split_bf16(float v, unsigned short& h, unsigned short& l) {
    unsigned int b = __float_as_uint(v);
    unsigned int hb = b & 0xFFFF0000u;
    h = (unsigned short)(hb >> 16);
    float r = v - __uint_as_float(hb);
    unsigned int lb = __float_as_uint(r);
    lb += 0x7FFFu + ((lb >> 16) & 1u);
    l = (unsigned short)(lb >> 16);
}

// ---------------------------------------------------------------------------
// Prep: build E B-fragments in MFMA layout (hi/lo split) + esqh = -|e|^2/2.
// R5: also zeroes the workspace prefix (cursor/loss_part/sumsFB) -- kills the
// separate hipMemsetAsync node (~15us/node overhead hypothesis test).
// ---------------------------------------------------------------------------
#define WSZERO (1024 + 1024 + KK * DD)

__global__ __launch_bounds__(64)
void vq_prep(const float* __restrict__ E, float4* __restrict__ Efrag,
             float* __restrict__ esqh, int* __restrict__ wsz) {
    // zero cursor + loss_part + sumsFB (67584 words over 4096 threads)
    int gtid = blockIdx.x * 64 + threadIdx.x;
    for (int i = gtid; i < WSZERO; i += 64 * (KK / 16)) wsz[i] = 0;

    int nt = blockIdx.x;
    int l = threadIdx.x;
    int n = nt * 16 + (l & 15);
    int kb = (l >> 4) * 8;
    float ss = 0.f;
    #pragma unroll
    for (int ks = 0; ks < 2; ++ks) {
        const float4* xp = (const float4*)(E + (size_t)n * DD + ks * 32 + kb);
        float4 a = xp[0], b = xp[1];
        float v[8] = {a.x, a.y, a.z, a.w, b.x, b.y, b.z, b.w};
        union { float4 f; unsigned short u[8]; } H, L;
        #pragma unroll
        for (int j = 0; j < 8; ++j) {
            unsigned short hh, ll;
            split_bf16(v[j], hh, ll);
            H.u[j] = hh; L.u[j] = ll;
            ss = fmaf(v[j], v[j], ss);
        }
        int fid = nt * 4 + ks * 2;
        Efrag[(size_t)(fid + 0) * 64 + l] = H.f;
        Efrag[(size_t)(fid + 1) * 64 + l] = L.f;
    }
    ss += __shfl_xor(ss, 16, 64);
    ss += __shfl_xor(ss, 32, 64);
    if (l < 16) esqh[nt * 16 + l] = -0.5f * ss;   // MFMA C-init: score = d - esq/2
}

// ---------------------------------------------------------------------------
// Main: split-bf16 MFMA distance GEMM + argmax(score) + light epilogue.
//
// R5: paired-tile consume. R2 (reg-prefetch) and R3 (LDS-staged) both sat at
// ~533 cyc/tile vs ~140 cyc issue -> per-tile dependency chain (ds_read
// latency -> 6-deep MFMA chain -> best-update VALU) with only ~2.8 resident
// waves/SIMD to cover it. Consume TWO 16-col tiles per barrier phase:
// 24 MFMA with 4 independent acc chains (was 12 with 2), 16 barriers
// (was 32). Phase C reverted to R3 rowlist (R4's direct atomics cost +37us
// in cross-XCD contention). (256,3): paired consume needs ~115 VGPR; cap
// 170 makes the R1 spill mode impossible at no occupancy cost (measured
// occupancy was ~2.8 waves/SIMD).
// ---------------------------------------------------------------------------
#define BM 64

__global__ __launch_bounds__(256, 3)
void vq_main(const float* __restrict__ X, const float* __restrict__ E,
             const float4* __restrict__ Efrag, const float* __restrict__ esqh,
             float* __restrict__ argf, float* __restrict__ mind,
             float* __restrict__ Z, int* __restrict__ cursor,
             int* __restrict__ rowlist, float* __restrict__ sumsFB,
             float* __restrict__ loss_part, int cap) {
    __shared__ float4 stg[2][2][8][64];   // [buf][tile][cg*4+fid][lane], 2 x 16KB
    __shared__ float redv[128];   // 64 rows x 2 col-groups
    __shared__ int redi[128];
    __shared__ int bidx[64];
    __shared__ float bsc[64];
    __shared__ float xsqs[64];
    __shared__ int fbflag[64];

    int tid = threadIdx.x;
    int lane = tid & 63, w = tid >> 6;
    int rg = w & 1, cg = w >> 1;
    int lc = lane & 15, lq = lane >> 4;

    size_t bb = (size_t)blockIdx.x * BM;
    size_t R0 = bb + rg * 32;

    // de-phase: blocks on the same XCD get consecutive start offsets in the
    // circular col-tile order
    int st = (blockIdx.x >> 3) & 31;

    // stage a PAIR of 16-col tiles (16 frags, 16KB). wave w stages 4 frags:
    // tile ti = w>>1, cg-half cgs = w&1, fids 0..3. LDS dest is wave-uniform
    // base; HW writes lane l at base + l*16 (linear), matching Efrag layout.
    auto stage_pair = [&](float4 (*sb)[8][64], int t0, int t1) {
        int ti = w >> 1, cgs = w & 1;
        int nt = (ti ? t1 : t0) & 31;
        const float4* gp = Efrag + ((size_t)(cgs * 32 + nt)) * 256 + lane;
        #pragma unroll
        for (int j = 0; j < 4; ++j)
            __builtin_amdgcn_global_load_lds((gv_t*)(gp + j * 64),
                                             (lv_t*)&sb[ti][cgs * 4 + j][0], 16, 0, 0);
    };

    // issue the first stage ASAP; the A-fragment build below covers its latency
    stage_pair(stg[0], st, st + 1);

    // A fragments: 2 m-tiles x 2 k-steps, hi+lo (32 VGPRs) + exact xsq
    bf16x8 ah[2][2], al[2][2];
    #pragma unroll
    for (int mt = 0; mt < 2; ++mt) {
        float xq = 0.f;
        #pragma unroll
        for (int ks = 0; ks < 2; ++ks) {
            const float4* xp =
                (const float4*)(X + (R0 + mt * 16 + lc) * DD + ks * 32 + lq * 8);
            float4 x0 = xp[0], x1 = xp[1];
            float v[8] = {x0.x, x0.y, x0.z, x0.w, x1.x, x1.y, x1.z, x1.w};
            union { bf16x8 s; unsigned short u[8]; } H, L;
            #pragma unroll
            for (int j = 0; j < 8; ++j) {
                unsigned short hh, ll;
                split_bf16(v[j], hh, ll);
                H.u[j] = hh; L.u[j] = ll;
                xq = fmaf(v[j], v[j], xq);
            }
            ah[mt][ks] = H.s;
            al[mt][ks] = L.s;
        }
        xq += __shfl_xor(xq, 16, 64);
        xq += __shfl_xor(xq, 32, 64);
        if (lane < 16) xsqs[rg * 32 + mt * 16 + lane] = xq;
    }

    float bestv[2][4];
    int besti[2][4];
    #pragma unroll
    for (int mt = 0; mt < 2; ++mt)
        #pragma unroll
        for (int r = 0; r < 4; ++r) { bestv[mt][r] = -3.402823466e38f; besti[mt][r] = 0; }

    const float* ep = esqh + cg * 512 + lc;

    // consume a staged tile-PAIR: 8x ds_read_b128 + 24 MFMA (4 indep chains)
    auto consume_pair = [&](float4 (*sb)[8][64], int ntp0, int ntp1) {
        float ec0 = ep[ntp0 * 16], ec1 = ep[ntp1 * 16];
        union { float4 f; bf16x8 s; } u[4], v[4];
        #pragma unroll
        for (int j = 0; j < 4; ++j) {
            u[j].f = sb[0][cg * 4 + j][lane];
            v[j].f = sb[1][cg * 4 + j][lane];
        }
        f32x4 acc[2][2];   // [tile][mt]
        #pragma unroll
        for (int mt = 0; mt < 2; ++mt) {
            acc[0][mt] = (f32x4){ec0, ec0, ec0, ec0};
            acc[1][mt] = (f32x4){ec1, ec1, ec1, ec1};
        }
        // 6 stages x {tile, mt} interleave: hihi(ks0), hihi(ks1), hilo(ks0),
        // hilo(ks1), lohi(ks0), lohi(ks1)  (same per-acc order as R3)
        #pragma unroll
        for (int mt = 0; mt < 2; ++mt) {
            acc[0][mt] = __builtin_amdgcn_mfma_f32_16x16x32_bf16(ah[mt][0], u[0].s, acc[0][mt], 0, 0, 0);
            acc[1][mt] = __builtin_amdgcn_mfma_f32_16x16x32_bf16(ah[mt][0], v[0].s, acc[1][mt], 0, 0, 0);
        }
        #pragma unroll
        for (int mt = 0; mt < 2; ++mt) {
            acc[0][mt] = __builtin_amdgcn_mfma_f32_16x16x32_bf16(ah[mt][1], u[2].s, acc[0][mt], 0, 0, 0);
            acc[1][mt] = __builtin_amdgcn_mfma_f32_16x16x32_bf16(ah[mt][1], v[2].s, acc[1][mt], 0, 0, 0);
        }
        #pragma unroll
        for (int mt = 0; mt < 2; ++mt) {
            acc[0][mt] = __builtin_amdgcn_mfma_f32_16x16x32_bf16(ah[mt][0], u[1].s, acc[0][mt], 0, 0, 0);
            acc[1][mt] = __builtin_amdgcn_mfma_f32_16x16x32_bf16(ah[mt][0], v[1].s, acc[1][mt], 0, 0, 0);
        }
        #pragma unroll
        for (int mt = 0; mt < 2; ++mt) {
            acc[0][mt] = __builtin_amdgcn_mfma_f32_16x16x32_bf16(ah[mt][1], u[3].s, acc[0][mt], 0, 0, 0);
            acc[1][mt] = __builtin_amdgcn_mfma_f32_16x16x32_bf16(ah[mt][1], v[3].s, acc[1][mt], 0, 0, 0);
        }
        #pragma unroll
        for (int mt = 0; mt < 2; ++mt) {
            acc[0][mt] = __builtin_amdgcn_mfma_f32_16x16x32_bf16(al[mt][0], u[0].s, acc[0][mt], 0, 0, 0);
            acc[1][mt] = __builtin_amdgcn_mfma_f32_16x16x32_bf16(al[mt][0], v[0].s, acc[1][mt], 0, 0, 0);
        }
        #pragma unroll
        for (int mt = 0; mt < 2; ++mt) {
            acc[0][mt] = __builtin_amdgcn_mfma_f32_16x16x32_bf16(al[mt][1], u[2].s, acc[0][mt], 0, 0, 0);
            acc[1][mt] = __builtin_amdgcn_mfma_f32_16x16x32_bf16(al[mt][1], v[2].s, acc[1][mt], 0, 0, 0);
        }
        int n0 = cg * 512 + ntp0 * 16 + lc;
        int n1 = cg * 512 + ntp1 * 16 + lc;
        #pragma unroll
        for (int mt = 0; mt < 2; ++mt)
            #pragma unroll
            for (int r = 0; r < 4; ++r) {
                float s0 = acc[0][mt][r];
                if (s0 > bestv[mt][r]) { bestv[mt][r] = s0; besti[mt][r] = n0; }
                float s1 = acc[1][mt][r];
                if (s1 > bestv[mt][r]) { bestv[mt][r] = s1; besti[mt][r] = n1; }
            }
    };

    // double-buffered sweep over 16 tile-pairs
    #pragma unroll 2
    for (int p = 0; p < 16; ++p) {
        int cur = p & 1;
        __syncthreads();                       // stg[cur] ready (vmcnt drained)
        if (p < 15) stage_pair(stg[cur ^ 1], st + 2 * p + 2, st + 2 * p + 3);
        consume_pair(stg[cur], (st + 2 * p) & 31, (st + 2 * p + 1) & 31);
    }

    // reduce across the 16 lanes holding one row (max score, low-index ties)
    #pragma unroll
    for (int off = 1; off <= 8; off <<= 1) {
        #pragma unroll
        for (int mt = 0; mt < 2; ++mt) {
            #pragma unroll
            for (int r = 0; r < 4; ++r) {
                float ov = __shfl_xor(bestv[mt][r], off, 64);
                int oi = __shfl_xor(besti[mt][r], off, 64);
                if (ov > bestv[mt][r] || (ov == bestv[mt][r] && oi < besti[mt][r])) {
                    bestv[mt][r] = ov; besti[mt][r] = oi;
                }
            }
        }
    }
    if (lc == 0) {
        #pragma unroll
        for (int mt = 0; mt < 2; ++mt)
            #pragma unroll
            for (int r = 0; r < 4; ++r) {
                int row = rg * 32 + mt * 16 + lq * 4 + r;
                redv[row * 2 + cg] = bestv[mt][r];
                redi[row * 2 + cg] = besti[mt][r];
            }
    }
    __syncthreads();
    if (tid < 64) {
        float v0 = redv[tid * 2], v1 = redv[tid * 2 + 1];
        int i0 = redi[tid * 2], i1 = redi[tid * 2 + 1];
        int pick = (v1 > v0 || (v1 == v0 && i1 < i0));
        bidx[tid] = pick ? i1 : i0;
        bsc[tid] = pick ? v1 : v0;
    }
    __syncthreads();

    // Phase B: one row per lane of wave 0 -> 64 concurrent cursor atomics
    if (tid < 64) {
        int row = tid;
        int bi = bidx[row];
        size_t grow = bb + row;
        float md = fmaf(-2.f, bsc[row], xsqs[row]);  // dist = xsq - 2*best
        mind[grow] = md;
        argf[grow] = (float)bi;
        int pos = atomicAdd(&cursor[bi], 1);
        if (pos < cap) {
            rowlist[(size_t)bi * cap + pos] = (int)grow;
            fbflag[row] = 0;
        } else {
            fbflag[row] = 1;
        }
        #pragma unroll
        for (int m = 32; m; m >>= 1) md += __shfl_xor(md, m, 64);
        if (tid == 0) atomicAdd(&loss_part[blockIdx.x & 1023], md);
    }
    __syncthreads();

    // Phase C: Z = E[argmin] gather stream
    #pragma unroll 4
    for (int it = 0; it < 16; ++it) {
        int row = w * 16 + it;
        int bi = bidx[row];
        size_t grow = bb + row;
        float e = E[(size_t)bi * DD + lane];
        Z[grow * DD + lane] = e;
        if (fbflag[row]) {
            float x = X[grow * DD + lane];
            atomicAdd(&sumsFB[(size_t)bi * DD + lane], x);
        }
    }
}

// ---------------------------------------------------------------------------
// Segment sum + cs + loss + ma/E_new, fully fused. One 1024-thread block per
// code k: 16 waves split the row list (4x shorter worst-cluster chain).
// ---------------------------------------------------------------------------
__global__ __launch_bounds__(1024)
void vq_sum_ema(const float* __restrict__ X, const int* __restrict__ rowlist,
                const int* __restrict__ cursor, const float* __restrict__ sumsFB,
                const float* __restrict__ cluster_sizes,
                const float* __restrict__ loss_part, const float* __restrict__ mavg,
                float* __restrict__ o_ma, float* __restrict__ o_enew,
                float* __restrict__ o_cs, float* __restrict__ o_loss, int cap) {
    __shared__ float part[16][64];
    __shared__ float redt[16];
    int k = blockIdx.x;
    int lane = threadIdx.x & 63, w = threadIdx.x >> 6;

    // total = sum_j gamma*cluster_sizes[j] + (1-gamma)*counts[j]
    float t = GAMMA * cluster_sizes[threadIdx.x] + OMG * (float)cursor[threadIdx.x];
    #pragma unroll
    for (int m = 32; m; m >>= 1) t += __shfl_xor(t, m, 64);
    if (lane == 0) redt[w] = t;
    __syncthreads();
    float total = 0.f;
    #pragma unroll
    for (int j = 0; j < 16; ++j) total += redt[j];

    float csr = GAMMA * cluster_sizes[k] + OMG * (float)cursor[k];
    float cs = (csr + ALPHA) / (1.0f + (ALPHA * (float)KK) / total);
    if (threadIdx.x == 0) o_cs[k] = cs;

    if (k == 0) {   // loss finalize
        __syncthreads();
        float t2 = loss_part[threadIdx.x];
        #pragma unroll
        for (int m = 32; m; m >>= 1) t2 += __shfl_xor(t2, m, 64);
        if (lane == 0) redt[w] = t2;
        __syncthreads();
        if (threadIdx.x == 0) {
            float l = 0.f;
            #pragma unroll
            for (int j = 0; j < 16; ++j) l += redt[j];
            o_loss[0] = BETA * (l / (float)NN);
        }
    }

    // segment sum over this code's rows (atomic-free), 16 waves
    int cnt = cursor[k];
    int nr = cnt < cap ? cnt : cap;
    const int* rl = rowlist + (size_t)k * cap;
    float acc = 0.f;
    #pragma unroll 4
    for (int i = w; i < nr; i += 16) {
        int r = rl[i];
        acc += X[(size_t)r * DD + lane];
    }
    part[w][lane] = acc;
    __syncthreads();
    if (w == 0) {
        float s = sumsFB[(size_t)k * DD + lane];
        #pragma unroll
        for (int j = 0; j < 16; ++j) s += part[j][lane];
        float ma = GAMMA * mavg[(size_t)k * DD + lane] + OMG * s;
        o_ma[(size_t)k * DD + lane] = ma;
        o_enew[(size_t)k * DD + lane] = ma / cs;
    }
}

// ---------------------------------------------------------------------------
extern "C" void kernel_launch(void* const* d_in, const int* in_sizes, int n_in,
                              void* d_out, int out_size, void* d_ws, size_t ws_size,
                              hipStream_t stream) {
    const float* X = (const float*)d_in[0];
    const float* E = (const float*)d_in[1];
    const float* cluster_sizes = (const float*)d_in[2];
    const float* moving_avg = (const float*)d_in[3];

    // Output layout: Z[N*D], loss[1], argmins[N], min_dist[N],
    //                E_new[K*D], cs[K], ma[K*D]
    float* out = (float*)d_out;
    float* o_Z = out;
    float* o_loss = o_Z + (size_t)NN * DD;
    float* o_arg = o_loss + 1;
    float* o_mind = o_arg + NN;
    float* o_enew = o_mind + NN;
    float* o_cs = o_enew + (size_t)KK * DD;
    float* o_ma = o_cs + KK;

    // Workspace (4B units):
    // [cursor 1024 i32][loss_part 1024 f][sumsFB 65536 f][esqh 1024 f]
    // [Efrag 65536 f][rowlist K*cap i32]
    int* cursor = (int*)d_ws;
    float* loss_part = (float*)d_ws + 1024;
    float* sumsFB = loss_part + 1024;
    float* esqh = sumsFB + (size_t)KK * DD;
    float4* Efrag = (float4*)(esqh + KK);
    int* rowlist = (int*)(esqh + KK + (size_t)KK * DD);

    size_t base_bytes = (size_t)(1024 + 1024 + KK * DD + KK + KK * DD) * 4;
    long cap_l = ((long)ws_size - (long)base_bytes) / (long)(KK * sizeof(int));
    int cap = cap_l < 0 ? 0 : (cap_l > 1024 ? 1024 : (int)cap_l);

    // 3 nodes: prep (also zeroes ws prefix) -> main -> sum_ema
    vq_prep<<<KK / 16, 64, 0, stream>>>(E, Efrag, esqh, cursor);
    vq_main<<<NN / BM, 256, 0, stream>>>(X, E, Efrag, esqh, o_arg, o_mind, o_Z,
                                         cursor, rowlist, sumsFB, loss_part, cap);
    vq_sum_ema<<<KK, 1024, 0, stream>>>(X, rowlist, cursor, sumsFB, cluster_sizes,
                                        loss_part, moving_avg, o_ma, o_enew,
                                        o_cs, o_loss, cap);
}